// Round 11
// baseline (258.338 us; speedup 1.0000x reference)
//
#include <hip/hip_runtime.h>

#define OBS_DIM 64
#define ACT_DIM 12
#define IN_DIM  76
#define HID     256
#define BATCH   1024
#define CAP     100000
#define NKT     48
#define NCHUNK  ((CAP + NKT - 1) / NKT)      /* 2084 */
#define LOG2E   1.4426950408889634f

/* keys16 record: [0,24576) frag-layout fp16 keys (32 slabs x 48 keys x 16B);
   [24576,24768) n2 fp32[48]; [24768,24960) padded vals fp32[48]; pad to 25088 */
#define REC_BYTES 25088
#define N2_OFF    24576

#define ROWT  128                             /* rows per gemm block (wave: 32) */
#define NRT   (BATCH / ROWT)                  /* 8 row-tiles */
#define CBLK  96                              /* chunk-strided blocks per row-tile */

typedef __attribute__((ext_vector_type(8))) _Float16 f16x8;
typedef __attribute__((ext_vector_type(4))) _Float16 f16x4;
typedef __attribute__((ext_vector_type(4))) float    f32x4;

// ---- fused pre-pass: (blocks < NCHUNK) repack keys fp32->fp16 frag records
// ---- (coalesced reads, LDS XOR-swizzled staging, coalesced writes);
// ---- (blocks >= NCHUNK) trunk. A is PRE-SCALED by 2*log2e.
__global__ __launch_bounds__(256) void np_pre(const float* __restrict__ obs,
                                              const float* __restrict__ act,
                                              const float* __restrict__ W,
                                              const float* __restrict__ bias,
                                              const float* __restrict__ gamma,
                                              const float* __restrict__ beta,
                                              const float* __restrict__ keys,
                                              const float* __restrict__ vals,
                                              char* __restrict__ keys16c,
                                              _Float16* __restrict__ A) {
    __shared__ __align__(16) char lbuf[24576];      // frag staging (swizzled slots)
    __shared__ float shred[256];
    const int t = threadIdx.x;
    if (blockIdx.x < NCHUNK) {
        // ---------- key repack ----------
        const int chunk = blockIdx.x;
        const int kb = chunk * NKT;
        const int wave = t >> 6;
        const int lane = t & 63;
        char* rec = keys16c + (size_t)chunk * REC_BYTES;
        const int k3 = lane >> 1;      // k-slab 0..31
        const int sub = lane & 1;      // 8B half of the 16B cell
#pragma unroll
        for (int kk = 0; kk < 12; ++kk) {
            const int key = wave * 12 + kk;
            const int gkey = kb + key;
            float4 f = make_float4(0.f, 0.f, 0.f, 0.f);
            if (gkey < CAP) f = ((const float4*)(keys + (size_t)gkey * HID))[lane];
            float p = fmaf(f.x, f.x, fmaf(f.y, f.y, fmaf(f.z, f.z, f.w * f.w)));
            f16x4 hv = {(_Float16)f.x, (_Float16)f.y, (_Float16)f.z, (_Float16)f.w};
            // slab k3 (768B), slot = key ^ (k3&7)  (48 % 8 == 0 -> bijective)
            *(f16x4*)(lbuf + k3 * 768 + ((key ^ (k3 & 7)) << 4) + sub * 8) = hv;
#pragma unroll
            for (int m = 1; m < 64; m <<= 1) p += __shfl_xor(p, m, 64);
            if (lane == 0) shred[key] = p;
        }
        __syncthreads();
        // coalesced writeback: 6 x 16B cells/thread at UNswizzled frag position
#pragma unroll
        for (int j = 0; j < 6; ++j) {
            const int c = j * 256 + t;          // cell = k3*48 + key
            const int ck3 = c / 48;
            const int ckey = c - ck3 * 48;
            *(f16x8*)(rec + (size_t)c * 16) =
                *(const f16x8*)(lbuf + ck3 * 768 + ((ckey ^ (ck3 & 7)) << 4));
        }
        if (t < NKT) {
            float* foot = (float*)(rec + N2_OFF);
            const bool okk = (kb + t) < CAP;
            foot[t] = okk ? -shred[t] * LOG2E : -1e37f;   // pad -> logit -inf
            foot[48 + t] = okk ? vals[kb + t] : 0.f;      // pad -> value 0
        }
    } else {
        // ---------- trunk ----------
        const int row = blockIdx.x - NCHUNK;
        float* x = shred;          // [0..75]
        float* red = shred + 80;   // [80..87]
        if (t < OBS_DIM) x[t] = obs[row * OBS_DIM + t];
        else if (t < IN_DIM) x[t] = act[row * ACT_DIM + (t - OBS_DIM)];
        __syncthreads();
        float h = bias[t];
#pragma unroll
        for (int k = 0; k < IN_DIM; ++k) h = fmaf(x[k], W[k * HID + t], h);
        float s1 = h, s2 = h * h;
#pragma unroll
        for (int m = 1; m < 64; m <<= 1) { s1 += __shfl_xor(s1, m, 64); s2 += __shfl_xor(s2, m, 64); }
        const int wave = t >> 6;
        if ((t & 63) == 0) { red[wave] = s1; red[4 + wave] = s2; }
        __syncthreads();
        const float S1 = red[0] + red[1] + red[2] + red[3];
        const float S2 = red[4] + red[5] + red[6] + red[7];
        const float mu = S1 * (1.0f / 256.0f);
        const float var = S2 * (1.0f / 256.0f) - mu * mu;
        const float rs = rsqrtf(var + 1e-5f);
        const float g = (h - mu) * rs * gamma[t] + beta[t];
        const float e = exp2f(g * (2.0f * LOG2E));
        const float ph = 1.0f - 2.0f / (e + 1.0f);
        A[row * HID + t] = (_Float16)(ph * (2.0f * LOG2E));
    }
}

// ------------- A-stationary fused GEMM + ONLINE softmax over chunks -------------
// Round-7 proven 2-buffer syncthreads pipeline, but NKT=48 -> LDS 50.2 KB ->
// THREE blocks/CU (round 10 proved the binder is issue/TLP, not prefetch depth:
// per-key cost was identical across drain-0 and counted-vmcnt schemes at
// 2 blocks/CU). CBLK=96 -> grid 768 = exactly 3 blocks/CU = 3 waves/SIMD;
// independently-barriered blocks cover each other's stalls. Per-wave shape
// unchanged (32 rows, af[2][8], 256 threads / (256,2): the only no-spill regime
// — rounds 1/3/6/8). Chunk sharers are 96 apart (96%8==0 -> same XCD, L2-served).
__global__ __launch_bounds__(256, 2) void np_gemm(const char* __restrict__ keys16c,
                                                  const _Float16* __restrict__ A,
                                                  float* __restrict__ pm,
                                                  float* __restrict__ pl,
                                                  float* __restrict__ pa) {
    const int rt = blockIdx.x / CBLK;
    const int cb = blockIdx.x % CBLK;
    const int t = threadIdx.x;
    const int lane = t & 63;
    const int wave = t >> 6;
    const int q = lane >> 4;      // quad within wave (k-chunk selector)
    const int rcol = lane & 15;   // row within a 16-row tile

    __shared__ __align__(16) char buf[2][REC_BYTES];  // 50176 B -> 3 blocks/CU

    const int rowbase = rt * ROWT + wave * 32;

    // 7 loads per wave per chunk: 6 x 16B key slice + 1 footer 16B (lanes<6)
#define DMAISSUE(C, IB) do {                                                          \
        const char* rec_ = keys16c + (size_t)(C) * REC_BYTES;                         \
        const char* gsrc_ = rec_ + wave * 6144 + lane * 16;                           \
        char* ldst_ = &buf[IB][0] + wave * 6144;                                      \
        _Pragma("unroll")                                                             \
        for (int j_ = 0; j_ < 6; ++j_) {                                              \
            __builtin_amdgcn_global_load_lds(                                         \
                (const __attribute__((address_space(1))) void*)(gsrc_ + j_ * 1024),   \
                (__attribute__((address_space(3))) void*)(ldst_ + j_ * 1024), 16, 0, 0); \
        }                                                                             \
        if (lane < 6) {                                                               \
            __builtin_amdgcn_global_load_lds(                                         \
                (const __attribute__((address_space(1))) void*)(rec_ + N2_OFF + wave * 96 + lane * 16), \
                (__attribute__((address_space(3))) void*)(&buf[IB][0] + N2_OFF + wave * 96), 16, 0, 0); \
        }                                                                             \
    } while (0)

    // ---- prologue: DMA first chunk, load stationary A fragments (2 row-tiles) ----
    int c = cb;
    DMAISSUE(c, 0);
    f16x8 af[2][8];
#pragma unroll
    for (int tb = 0; tb < 2; ++tb) {
        const f16x8* ap = (const f16x8*)(A + (size_t)(rowbase + tb * 16 + rcol) * HID + q * 8);
#pragma unroll
        for (int s = 0; s < 8; ++s) af[tb][s] = ap[s * 4];
    }
    // online softmax state per row-tile (per-lane: row rcol x key-quad q slice)
    float M[2]  = {-3e38f, -3e38f};
    float Lr[2] = {0.f, 0.f};
    float Ar[2] = {0.f, 0.f};
    __syncthreads();   // drains vmcnt: chunk0 DMA + af loads

    int ib = 0;
#pragma unroll 1
    for (; c < NCHUNK; ) {
        const int cn = c + CBLK;
        if (cn < NCHUNK) DMAISSUE(cn, ib ^ 1);   // prefetch next chunk

        const _Float16* bt16 = (const _Float16*)&buf[ib][0];
        const float* n2s = (const float*)(&buf[ib][0] + N2_OFF);
        const float* vvs = n2s + 48;

        // acc init = nn: MFMA C-in carries -||k||^2*log2e (reg r <-> key q*4+r)
        f32x4 acc[2][3];
#pragma unroll
        for (int cc = 0; cc < 3; ++cc) {
            const f32x4 nn = *(const f32x4*)&n2s[cc * 16 + q * 4];
            acc[0][cc] = nn;
            acc[1][cc] = nn;
        }
#pragma unroll
        for (int s = 0; s < 8; ++s) {
#pragma unroll
            for (int cc = 0; cc < 3; ++cc) {
                const f16x8 bf = *(const f16x8*)(bt16 + (s * 4 + q) * 384 + ((cc * 16 + rcol) << 3));
                // swapped operands: C[key][row]; one bf read feeds both row-tiles
                acc[0][cc] = __builtin_amdgcn_mfma_f32_16x16x32_f16(bf, af[0][s], acc[0][cc], 0, 0, 0);
                acc[1][cc] = __builtin_amdgcn_mfma_f32_16x16x32_f16(bf, af[1][s], acc[1][cc], 0, 0, 0);
            }
        }

        // ---- per-chunk ONLINE update; acc already holds base-2 logits ----
#pragma unroll
        for (int tb = 0; tb < 2; ++tb) {
            const f32x4 mv = __builtin_elementwise_max(
                __builtin_elementwise_max(acc[tb][0], acc[tb][1]), acc[tb][2]);
            const float pmax = fmaxf(fmaxf(mv[0], mv[1]), fmaxf(mv[2], mv[3]));
            const float Mn = fmaxf(M[tb], pmax);
            const float sc = exp2f(M[tb] - Mn);   // first chunk: exp2(-inf)=0, L=A=0 anyway
            const f32x4 Mn4 = {Mn, Mn, Mn, Mn};
            f32x4 ws  = {0.f, 0.f, 0.f, 0.f};
            f32x4 wvs = {0.f, 0.f, 0.f, 0.f};
#pragma unroll
            for (int cc = 0; cc < 3; ++cc) {
                const f32x4 e = acc[tb][cc] - Mn4;
                const f32x4 w = {exp2f(e[0]), exp2f(e[1]), exp2f(e[2]), exp2f(e[3])};
                const f32x4 vl = *(const f32x4*)&vvs[cc * 16 + q * 4];
                ws  += w;
                wvs += w * vl;
            }
            const float ls = (ws[0] + ws[1]) + (ws[2] + ws[3]);
            const float as = (wvs[0] + wvs[1]) + (wvs[2] + wvs[3]);
            Lr[tb] = fmaf(Lr[tb], sc, ls);
            Ar[tb] = fmaf(Ar[tb], sc, as);
            M[tb] = Mn;
        }

        __syncthreads();   // next DMA drained + all reads of buf[ib] done
        c = cn; ib ^= 1;
    }
#undef DMAISSUE

    // ---- epilogue: merge across the 4 q-lanes of each row, write one partial ----
#pragma unroll
    for (int tb = 0; tb < 2; ++tb) {
        float m = M[tb], l = Lr[tb], a = Ar[tb];
#pragma unroll
        for (int sh = 16; sh < 64; sh <<= 1) {
            const float mo = __shfl_xor(m, sh, 64);
            const float lo = __shfl_xor(l, sh, 64);
            const float ao = __shfl_xor(a, sh, 64);
            const float mn = fmaxf(m, mo);
            const float s0 = exp2f(m - mn);
            const float s1 = exp2f(mo - mn);
            l = fmaf(l, s0, lo * s1);
            a = fmaf(a, s0, ao * s1);
            m = mn;
        }
        if (lane < 16) {
            const int row = rowbase + tb * 16 + lane;
            const size_t idx = (size_t)cb * BATCH + row;
            pm[idx] = m; pl[idx] = l; pa[idx] = a;
        }
    }
}

// ------------- single merge: 96-way per row, write q1==q2 -------------
__global__ __launch_bounds__(256) void np_merge(const float* __restrict__ pm,
                                                const float* __restrict__ pl,
                                                const float* __restrict__ pa,
                                                float* __restrict__ out) {
    const int t = threadIdx.x;
    const int row = blockIdx.x * 64 + (t & 63);
    const int cg = t >> 6;
    float M = -3e38f, L = 0.f, Acc = 0.f;
#pragma unroll 1
    for (int cb = cg; cb < CBLK; cb += 4) {
        const size_t idx = (size_t)cb * BATCH + row;
        const float m = pm[idx], l = pl[idx], a = pa[idx];
        const float Mn = fmaxf(M, m);
        const float s0 = exp2f(M - Mn);
        const float s1 = exp2f(m - Mn);
        L = fmaf(L, s0, l * s1);
        Acc = fmaf(Acc, s0, a * s1);
        M = Mn;
    }
    __shared__ float sm[256], sl[256], sa[256];
    sm[t] = M; sl[t] = L; sa[t] = Acc;
    __syncthreads();
    if (t < 64) {
        const float M0 = sm[t], M1 = sm[t + 64], M2 = sm[t + 128], M3 = sm[t + 192];
        const float Mf = fmaxf(fmaxf(M0, M1), fmaxf(M2, M3));
        const float e0 = exp2f(M0 - Mf), e1 = exp2f(M1 - Mf), e2 = exp2f(M2 - Mf), e3 = exp2f(M3 - Mf);
        const float Lf = sl[t] * e0 + sl[t + 64] * e1 + sl[t + 128] * e2 + sl[t + 192] * e3;
        const float Af = sa[t] * e0 + sa[t + 64] * e1 + sa[t + 128] * e2 + sa[t + 192] * e3;
        const float qv = Af / Lf;
        const int r = blockIdx.x * 64 + t;
        out[r] = qv;
        out[BATCH + r] = qv;
    }
}

extern "C" void kernel_launch(void* const* d_in, const int* in_sizes, int n_in,
                              void* d_out, int out_size, void* d_ws, size_t ws_size,
                              hipStream_t stream) {
    const float* obs   = (const float*)d_in[0];
    const float* act   = (const float*)d_in[1];
    const float* W     = (const float*)d_in[2];
    const float* bias  = (const float*)d_in[3];
    const float* gamma = (const float*)d_in[4];
    const float* beta  = (const float*)d_in[5];
    const float* keys  = (const float*)d_in[6];
    const float* vals  = (const float*)d_in[7];
    float* out = (float*)d_out;

    char* w = (char*)d_ws;
    char* keys16c = w;                                     // 52.3 MB records
    w += (size_t)NCHUNK * REC_BYTES;
    _Float16* A = (_Float16*)w;                            // 512 KB
    w += (size_t)BATCH * HID * sizeof(_Float16);
    float* pm = (float*)w;                                 // 3 x 384 KB
    float* pl = pm + (size_t)CBLK * BATCH;
    float* pa = pl + (size_t)CBLK * BATCH;

    np_pre<<<NCHUNK + BATCH, 256, 0, stream>>>(obs, act, W, bias, gamma, beta,
                                               keys, vals, keys16c, A);
    np_gemm<<<NRT * CBLK, 256, 0, stream>>>(keys16c, A, pm, pl, pa);
    np_merge<<<BATCH / 64, 256, 0, stream>>>(pm, pl, pa, out);
}

// Round 12
// 248.995 us; speedup vs baseline: 1.0375x; 1.0375x over previous
//
#include <hip/hip_runtime.h>

#define OBS_DIM 64
#define ACT_DIM 12
#define IN_DIM  76
#define HID     256
#define BATCH   1024
#define CAP     100000
#define NKT     64
#define NCHUNK  ((CAP + NKT - 1) / NKT)      /* 1563 */
#define LOG2E   1.4426950408889634f

/* keys16 record: [0,32768) frag-layout fp16 keys; [32768,33024) n2 fp32[64];
   [33024,33280) padded vals fp32[64]; [33280,33792) pad (DMA'd, never read) */
#define REC_BYTES 33792
#define N2_OFF    32768

#define ROWT  128                             /* rows per gemm block (wave: 32) */
#define NRT   (BATCH / ROWT)                  /* 8 row-tiles */
#define CBLK  64                              /* chunk-strided blocks per row-tile */

typedef __attribute__((ext_vector_type(8))) _Float16 f16x8;
typedef __attribute__((ext_vector_type(4))) _Float16 f16x4;
typedef __attribute__((ext_vector_type(4))) float    f32x4;

// ---- fused pre-pass: (blocks < NCHUNK) repack keys fp32->fp16 frag records;
// ---- (blocks >= NCHUNK) trunk. A is PRE-SCALED by 2*log2e.
// Repack: coalesced 1KB/wave key reads; ||k||^2 via 2 shfl steps + LDS partials
// (round 9 used a 6-deep chained shfl butterfly per key = 96 serialized ~30cyc
// DS ops per wave — the serial-reduction mistake; this cuts the chain to 2).
__global__ __launch_bounds__(256) void np_pre(const float* __restrict__ obs,
                                              const float* __restrict__ act,
                                              const float* __restrict__ W,
                                              const float* __restrict__ bias,
                                              const float* __restrict__ gamma,
                                              const float* __restrict__ beta,
                                              const float* __restrict__ keys,
                                              const float* __restrict__ vals,
                                              char* __restrict__ keys16c,
                                              _Float16* __restrict__ A) {
    __shared__ __align__(16) char lbuf[32768];      // frag staging (swizzled slots)
    __shared__ float shred[256];
    __shared__ float sqp[64][17];                   // per-key 16 group-partials (+1 pad)
    const int t = threadIdx.x;
    if (blockIdx.x < NCHUNK) {
        // ---------- key repack ----------
        const int chunk = blockIdx.x;
        const int kb = chunk * NKT;
        const int wave = t >> 6;
        const int lane = t & 63;
        char* rec = keys16c + (size_t)chunk * REC_BYTES;
        const int k3 = lane >> 1;      // k-slab 0..31
        const int sub = lane & 1;      // 8B half of the 16B cell
#pragma unroll
        for (int kk = 0; kk < 16; ++kk) {
            const int key = wave * 16 + kk;
            const int gkey = kb + key;
            float4 f = make_float4(0.f, 0.f, 0.f, 0.f);
            if (gkey < CAP) f = ((const float4*)(keys + (size_t)gkey * HID))[lane];
            float p = fmaf(f.x, f.x, fmaf(f.y, f.y, fmaf(f.z, f.z, f.w * f.w)));
            f16x4 hv = {(_Float16)f.x, (_Float16)f.y, (_Float16)f.z, (_Float16)f.w};
            // slab k3 (1KB), slot = key ^ (k3&7)  (bijective within slab)
            *(f16x4*)(lbuf + k3 * 1024 + ((key ^ (k3 & 7)) << 4) + sub * 8) = hv;
            // short reduction: 2 shuffle steps, then LDS partial per 4-lane group
            p += __shfl_xor(p, 1, 64);
            p += __shfl_xor(p, 2, 64);
            if ((lane & 3) == 0) sqp[key][lane >> 2] = p;
        }
        __syncthreads();
        // coalesced writeback: 8 x 16B cells/thread at UNswizzled frag position
#pragma unroll
        for (int j = 0; j < 8; ++j) {
            const int c = j * 256 + t;          // cell = k3*64 + key
            const int ck3 = c >> 6;
            const int ckey = c & 63;
            *(f16x8*)(rec + (size_t)c * 16) =
                *(const f16x8*)(lbuf + ck3 * 1024 + ((ckey ^ (ck3 & 7)) << 4));
        }
        if (t < NKT) {
            float s = 0.f;
#pragma unroll
            for (int i = 0; i < 16; ++i) s += sqp[t][i];
            float* foot = (float*)(rec + N2_OFF);
            const bool okk = (kb + t) < CAP;
            foot[t] = okk ? -s * LOG2E : -1e37f;          // pad -> logit -inf
            foot[64 + t] = okk ? vals[kb + t] : 0.f;      // pad -> value 0
        }
    } else {
        // ---------- trunk ----------
        const int row = blockIdx.x - NCHUNK;
        float* x = shred;          // [0..75]
        float* red = shred + 80;   // [80..87]
        if (t < OBS_DIM) x[t] = obs[row * OBS_DIM + t];
        else if (t < IN_DIM) x[t] = act[row * ACT_DIM + (t - OBS_DIM)];
        __syncthreads();
        float h = bias[t];
#pragma unroll
        for (int k = 0; k < IN_DIM; ++k) h = fmaf(x[k], W[k * HID + t], h);
        float s1 = h, s2 = h * h;
#pragma unroll
        for (int m = 1; m < 64; m <<= 1) { s1 += __shfl_xor(s1, m, 64); s2 += __shfl_xor(s2, m, 64); }
        const int wave = t >> 6;
        if ((t & 63) == 0) { red[wave] = s1; red[4 + wave] = s2; }
        __syncthreads();
        const float S1 = red[0] + red[1] + red[2] + red[3];
        const float S2 = red[4] + red[5] + red[6] + red[7];
        const float mu = S1 * (1.0f / 256.0f);
        const float var = S2 * (1.0f / 256.0f) - mu * mu;
        const float rs = rsqrtf(var + 1e-5f);
        const float g = (h - mu) * rs * gamma[t] + beta[t];
        const float e = exp2f(g * (2.0f * LOG2E));
        const float ph = 1.0f - 2.0f / (e + 1.0f);
        // pre-scale by 2*log2e: MFMA output = 2*log2e*(phi.k); |val|<=2.89 fits fp16
        A[row * HID + t] = (_Float16)(ph * (2.0f * LOG2E));
    }
}

// ------------- A-stationary fused GEMM + ONLINE softmax over chunks -------------
// VERBATIM round-9 kernel (79.4us, VGPR 88, zero spill — best measured).
// Five structural variants (drain-0 / counted-vmcnt / NKT 48|64 / 2|3 blocks/CU)
// all land at 25.5-26 ns/key*CU: this structure's empirical floor.
__global__ __launch_bounds__(256, 2) void np_gemm(const char* __restrict__ keys16c,
                                                  const _Float16* __restrict__ A,
                                                  float* __restrict__ pm,
                                                  float* __restrict__ pl,
                                                  float* __restrict__ pa) {
    const int rt = blockIdx.x / CBLK;
    const int cb = blockIdx.x % CBLK;
    const int t = threadIdx.x;
    const int lane = t & 63;
    const int wave = t >> 6;
    const int q = lane >> 4;      // quad within wave (k-chunk selector)
    const int rcol = lane & 15;   // row within a 16-row tile

    __shared__ __align__(16) char buf[2][REC_BYTES];  // 67584 B -> 2 blocks/CU

    const int rowbase = rt * ROWT + wave * 32;

#define DMAISSUE(C, IB) do {                                                          \
        const char* rec_ = keys16c + (size_t)(C) * REC_BYTES;                         \
        const char* gsrc_ = rec_ + wave * 1024 + lane * 16;                           \
        char* ldst_ = &buf[IB][0] + wave * 1024;                                      \
        _Pragma("unroll")                                                             \
        for (int j_ = 0; j_ < 8; ++j_) {                                              \
            __builtin_amdgcn_global_load_lds(                                         \
                (const __attribute__((address_space(1))) void*)(gsrc_ + j_ * 4096),   \
                (__attribute__((address_space(3))) void*)(ldst_ + j_ * 4096), 16, 0, 0); \
        }                                                                             \
        if (wave == 0) {                                                              \
            __builtin_amdgcn_global_load_lds(                                         \
                (const __attribute__((address_space(1))) void*)(rec_ + N2_OFF + lane * 16), \
                (__attribute__((address_space(3))) void*)(&buf[IB][0] + N2_OFF), 16, 0, 0); \
        }                                                                             \
    } while (0)

    // ---- prologue: DMA first chunk, load stationary A fragments (2 row-tiles) ----
    int c = cb;
    DMAISSUE(c, 0);
    f16x8 af[2][8];
#pragma unroll
    for (int tb = 0; tb < 2; ++tb) {
        const f16x8* ap = (const f16x8*)(A + (size_t)(rowbase + tb * 16 + rcol) * HID + q * 8);
#pragma unroll
        for (int s = 0; s < 8; ++s) af[tb][s] = ap[s * 4];
    }
    // online softmax state per row-tile (per-lane: row rcol x key-quad q slice)
    float M[2]  = {-3e38f, -3e38f};
    float Lr[2] = {0.f, 0.f};
    float Ar[2] = {0.f, 0.f};
    __syncthreads();   // drains vmcnt: chunk0 DMA + af loads

    int ib = 0;
#pragma unroll 1
    for (; c < NCHUNK; ) {
        const int cn = c + CBLK;
        if (cn < NCHUNK) DMAISSUE(cn, ib ^ 1);   // prefetch next chunk

        const _Float16* bt16 = (const _Float16*)&buf[ib][0];
        const float* n2s = (const float*)(&buf[ib][0] + N2_OFF);
        const float* vvs = n2s + 64;

        // acc init = nn: MFMA C-in carries -||k||^2*log2e (reg r <-> key q*4+r)
        f32x4 acc[2][4];
#pragma unroll
        for (int cc = 0; cc < 4; ++cc) {
            const f32x4 nn = *(const f32x4*)&n2s[cc * 16 + q * 4];
            acc[0][cc] = nn;
            acc[1][cc] = nn;
        }
#pragma unroll
        for (int s = 0; s < 8; ++s) {
#pragma unroll
            for (int cc = 0; cc < 4; ++cc) {
                const f16x8 bf = *(const f16x8*)(bt16 + (((s * 4 + q) * 64 + cc * 16 + rcol) << 3));
                // swapped operands: C[key][row]; one bf read feeds both row-tiles
                acc[0][cc] = __builtin_amdgcn_mfma_f32_16x16x32_f16(bf, af[0][s], acc[0][cc], 0, 0, 0);
                acc[1][cc] = __builtin_amdgcn_mfma_f32_16x16x32_f16(bf, af[1][s], acc[1][cc], 0, 0, 0);
            }
        }

        // ---- per-chunk ONLINE update; acc already holds base-2 logits ----
#pragma unroll
        for (int tb = 0; tb < 2; ++tb) {
            const f32x4 mv = __builtin_elementwise_max(
                __builtin_elementwise_max(acc[tb][0], acc[tb][1]),
                __builtin_elementwise_max(acc[tb][2], acc[tb][3]));
            const float pmax = fmaxf(fmaxf(mv[0], mv[1]), fmaxf(mv[2], mv[3]));
            const float Mn = fmaxf(M[tb], pmax);
            const float sc = exp2f(M[tb] - Mn);   // first chunk: exp2(-inf)=0, L=A=0 anyway
            const f32x4 Mn4 = {Mn, Mn, Mn, Mn};
            f32x4 ws  = {0.f, 0.f, 0.f, 0.f};
            f32x4 wvs = {0.f, 0.f, 0.f, 0.f};
#pragma unroll
            for (int cc = 0; cc < 4; ++cc) {
                const f32x4 e = acc[tb][cc] - Mn4;
                const f32x4 w = {exp2f(e[0]), exp2f(e[1]), exp2f(e[2]), exp2f(e[3])};
                const f32x4 vl = *(const f32x4*)&vvs[cc * 16 + q * 4];
                ws  += w;
                wvs += w * vl;
            }
            const float ls = (ws[0] + ws[1]) + (ws[2] + ws[3]);
            const float as = (wvs[0] + wvs[1]) + (wvs[2] + wvs[3]);
            Lr[tb] = fmaf(Lr[tb], sc, ls);
            Ar[tb] = fmaf(Ar[tb], sc, as);
            M[tb] = Mn;
        }

        __syncthreads();   // next DMA drained + all reads of buf[ib] done
        c = cn; ib ^= 1;
    }
#undef DMAISSUE

    // ---- epilogue: merge across the 4 q-lanes of each row, write one partial ----
#pragma unroll
    for (int tb = 0; tb < 2; ++tb) {
        float m = M[tb], l = Lr[tb], a = Ar[tb];
#pragma unroll
        for (int sh = 16; sh < 64; sh <<= 1) {
            const float mo = __shfl_xor(m, sh, 64);
            const float lo = __shfl_xor(l, sh, 64);
            const float ao = __shfl_xor(a, sh, 64);
            const float mn = fmaxf(m, mo);
            const float s0 = exp2f(m - mn);
            const float s1 = exp2f(mo - mn);
            l = fmaf(l, s0, lo * s1);
            a = fmaf(a, s0, ao * s1);
            m = mn;
        }
        if (lane < 16) {
            const int row = rowbase + tb * 16 + lane;
            const size_t idx = (size_t)cb * BATCH + row;
            pm[idx] = m; pl[idx] = l; pa[idx] = a;
        }
    }
}

// ------------- single merge: 64-way per row, write q1==q2 -------------
__global__ __launch_bounds__(256) void np_merge(const float* __restrict__ pm,
                                                const float* __restrict__ pl,
                                                const float* __restrict__ pa,
                                                float* __restrict__ out) {
    const int t = threadIdx.x;
    const int row = blockIdx.x * 64 + (t & 63);
    const int cg = t >> 6;
    float M = -3e38f, L = 0.f, Acc = 0.f;
#pragma unroll 1
    for (int cb = cg; cb < CBLK; cb += 4) {
        const size_t idx = (size_t)cb * BATCH + row;
        const float m = pm[idx], l = pl[idx], a = pa[idx];
        const float Mn = fmaxf(M, m);
        const float s0 = exp2f(M - Mn);
        const float s1 = exp2f(m - Mn);
        L = fmaf(L, s0, l * s1);
        Acc = fmaf(Acc, s0, a * s1);
        M = Mn;
    }
    __shared__ float sm[256], sl[256], sa[256];
    sm[t] = M; sl[t] = L; sa[t] = Acc;
    __syncthreads();
    if (t < 64) {
        const float M0 = sm[t], M1 = sm[t + 64], M2 = sm[t + 128], M3 = sm[t + 192];
        const float Mf = fmaxf(fmaxf(M0, M1), fmaxf(M2, M3));
        const float e0 = exp2f(M0 - Mf), e1 = exp2f(M1 - Mf), e2 = exp2f(M2 - Mf), e3 = exp2f(M3 - Mf);
        const float Lf = sl[t] * e0 + sl[t + 64] * e1 + sl[t + 128] * e2 + sl[t + 192] * e3;
        const float Af = sa[t] * e0 + sa[t + 64] * e1 + sa[t + 128] * e2 + sa[t + 192] * e3;
        const float qv = Af / Lf;
        const int r = blockIdx.x * 64 + t;
        out[r] = qv;
        out[BATCH + r] = qv;
    }
}

extern "C" void kernel_launch(void* const* d_in, const int* in_sizes, int n_in,
                              void* d_out, int out_size, void* d_ws, size_t ws_size,
                              hipStream_t stream) {
    const float* obs   = (const float*)d_in[0];
    const float* act   = (const float*)d_in[1];
    const float* W     = (const float*)d_in[2];
    const float* bias  = (const float*)d_in[3];
    const float* gamma = (const float*)d_in[4];
    const float* beta  = (const float*)d_in[5];
    const float* keys  = (const float*)d_in[6];
    const float* vals  = (const float*)d_in[7];
    float* out = (float*)d_out;

    char* w = (char*)d_ws;
    char* keys16c = w;                                     // 52.8 MB records
    w += (size_t)NCHUNK * REC_BYTES;
    _Float16* A = (_Float16*)w;                            // 512 KB
    w += (size_t)BATCH * HID * sizeof(_Float16);
    float* pm = (float*)w;                                 // 3 x 256 KB
    float* pl = pm + (size_t)CBLK * BATCH;
    float* pa = pl + (size_t)CBLK * BATCH;

    np_pre<<<NCHUNK + BATCH, 256, 0, stream>>>(obs, act, W, bias, gamma, beta,
                                               keys, vals, keys16c, A);
    np_gemm<<<NRT * CBLK, 256, 0, stream>>>(keys16c, A, pm, pl, pa);
    np_merge<<<BATCH / 64, 256, 0, stream>>>(pm, pl, pa, out);
}

// Round 13
// 247.964 us; speedup vs baseline: 1.0418x; 1.0042x over previous
//
#include <hip/hip_runtime.h>

#define OBS_DIM 64
#define ACT_DIM 12
#define IN_DIM  76
#define HID     256
#define BATCH   1024
#define CAP     100000
#define NKT     64
#define NCHUNK  ((CAP + NKT - 1) / NKT)      /* 1563 */
#define LOG2E   1.4426950408889634f

/* keys16 record: [0,32768) frag-layout fp16 keys; [32768,33024) n2 fp32[64];
   [33024,33280) padded vals fp32[64]; [33280,33792) pad (DMA'd, never read) */
#define REC_BYTES 33792
#define N2_OFF    32768

#define ROWT  128                             /* rows per gemm block (wave: 32) */
#define NRT   (BATCH / ROWT)                  /* 8 row-tiles */
#define CBLK  64                              /* chunk-strided blocks per row-tile */

typedef __attribute__((ext_vector_type(8))) _Float16 f16x8;
typedef __attribute__((ext_vector_type(4))) _Float16 f16x4;
typedef __attribute__((ext_vector_type(4))) float    f32x4;

// ---- fused pre-pass: (blocks < NCHUNK) repack keys fp32->fp16 frag records;
// ---- (blocks >= NCHUNK) trunk. A is PRE-SCALED by 2*log2e.
// Repack: the 16 coalesced 1KB/wave key loads are BATCH-ISSUED into registers
// first (64 VGPR), THEN processed — the round-12 loop consumed each load
// immediately, so the compiler's auto-waitcnt exposed ~700cy of L2/HBM latency
// 16x per block (G7 violation). Processing of elem i now waits only on load i.
__global__ __launch_bounds__(256) void np_pre(const float* __restrict__ obs,
                                              const float* __restrict__ act,
                                              const float* __restrict__ W,
                                              const float* __restrict__ bias,
                                              const float* __restrict__ gamma,
                                              const float* __restrict__ beta,
                                              const float* __restrict__ keys,
                                              const float* __restrict__ vals,
                                              char* __restrict__ keys16c,
                                              _Float16* __restrict__ A) {
    __shared__ __align__(16) char lbuf[32768];      // frag staging (swizzled slots)
    __shared__ float shred[256];
    __shared__ float sqp[64][17];                   // per-key 16 group-partials (+1 pad)
    const int t = threadIdx.x;
    if (blockIdx.x < NCHUNK) {
        // ---------- key repack ----------
        const int chunk = blockIdx.x;
        const int kb = chunk * NKT;
        const int wave = t >> 6;
        const int lane = t & 63;
        char* rec = keys16c + (size_t)chunk * REC_BYTES;
        const int k3 = lane >> 1;      // k-slab 0..31
        const int sub = lane & 1;      // 8B half of the 16B cell
        // phase 1: issue all 16 coalesced loads back-to-back
        float4 fbuf[16];
#pragma unroll
        for (int kk = 0; kk < 16; ++kk) {
            const int gkey = kb + wave * 16 + kk;
            fbuf[kk] = make_float4(0.f, 0.f, 0.f, 0.f);
            if (gkey < CAP) fbuf[kk] = ((const float4*)(keys + (size_t)gkey * HID))[lane];
        }
        // phase 2: convert + stage + sq partials
#pragma unroll
        for (int kk = 0; kk < 16; ++kk) {
            const int key = wave * 16 + kk;
            const float4 f = fbuf[kk];
            float p = fmaf(f.x, f.x, fmaf(f.y, f.y, fmaf(f.z, f.z, f.w * f.w)));
            f16x4 hv = {(_Float16)f.x, (_Float16)f.y, (_Float16)f.z, (_Float16)f.w};
            // slab k3 (1KB), slot = key ^ (k3&7)  (bijective within slab)
            *(f16x4*)(lbuf + k3 * 1024 + ((key ^ (k3 & 7)) << 4) + sub * 8) = hv;
            p += __shfl_xor(p, 1, 64);
            p += __shfl_xor(p, 2, 64);
            if ((lane & 3) == 0) sqp[key][lane >> 2] = p;
        }
        __syncthreads();
        // coalesced writeback: 8 x 16B cells/thread at UNswizzled frag position
#pragma unroll
        for (int j = 0; j < 8; ++j) {
            const int c = j * 256 + t;          // cell = k3*64 + key
            const int ck3 = c >> 6;
            const int ckey = c & 63;
            *(f16x8*)(rec + (size_t)c * 16) =
                *(const f16x8*)(lbuf + ck3 * 1024 + ((ckey ^ (ck3 & 7)) << 4));
        }
        if (t < NKT) {
            float s = 0.f;
#pragma unroll
            for (int i = 0; i < 16; ++i) s += sqp[t][i];
            float* foot = (float*)(rec + N2_OFF);
            const bool okk = (kb + t) < CAP;
            foot[t] = okk ? -s * LOG2E : -1e37f;          // pad -> logit -inf
            foot[64 + t] = okk ? vals[kb + t] : 0.f;      // pad -> value 0
        }
    } else {
        // ---------- trunk ----------
        const int row = blockIdx.x - NCHUNK;
        float* x = shred;          // [0..75]
        float* red = shred + 80;   // [80..87]
        if (t < OBS_DIM) x[t] = obs[row * OBS_DIM + t];
        else if (t < IN_DIM) x[t] = act[row * ACT_DIM + (t - OBS_DIM)];
        __syncthreads();
        float h = bias[t];
#pragma unroll
        for (int k = 0; k < IN_DIM; ++k) h = fmaf(x[k], W[k * HID + t], h);
        float s1 = h, s2 = h * h;
#pragma unroll
        for (int m = 1; m < 64; m <<= 1) { s1 += __shfl_xor(s1, m, 64); s2 += __shfl_xor(s2, m, 64); }
        const int wave = t >> 6;
        if ((t & 63) == 0) { red[wave] = s1; red[4 + wave] = s2; }
        __syncthreads();
        const float S1 = red[0] + red[1] + red[2] + red[3];
        const float S2 = red[4] + red[5] + red[6] + red[7];
        const float mu = S1 * (1.0f / 256.0f);
        const float var = S2 * (1.0f / 256.0f) - mu * mu;
        const float rs = rsqrtf(var + 1e-5f);
        const float g = (h - mu) * rs * gamma[t] + beta[t];
        const float e = exp2f(g * (2.0f * LOG2E));
        const float ph = 1.0f - 2.0f / (e + 1.0f);
        // pre-scale by 2*log2e: MFMA output = 2*log2e*(phi.k); |val|<=2.89 fits fp16
        A[row * HID + t] = (_Float16)(ph * (2.0f * LOG2E));
    }
}

// ------------- A-stationary fused GEMM + ONLINE softmax over chunks -------------
// VERBATIM round-9/12 kernel (80 us, VGPR 88, zero spill — best measured).
// Five structural variants (drain-0 / counted-vmcnt / NKT 48|64 / 2|3 blocks/CU)
// all land at 25.5-26 ns/key*CU: this structure's empirical floor.
__global__ __launch_bounds__(256, 2) void np_gemm(const char* __restrict__ keys16c,
                                                  const _Float16* __restrict__ A,
                                                  float* __restrict__ pm,
                                                  float* __restrict__ pl,
                                                  float* __restrict__ pa) {
    const int rt = blockIdx.x / CBLK;
    const int cb = blockIdx.x % CBLK;
    const int t = threadIdx.x;
    const int lane = t & 63;
    const int wave = t >> 6;
    const int q = lane >> 4;      // quad within wave (k-chunk selector)
    const int rcol = lane & 15;   // row within a 16-row tile

    __shared__ __align__(16) char buf[2][REC_BYTES];  // 67584 B -> 2 blocks/CU

    const int rowbase = rt * ROWT + wave * 32;

#define DMAISSUE(C, IB) do {                                                          \
        const char* rec_ = keys16c + (size_t)(C) * REC_BYTES;                         \
        const char* gsrc_ = rec_ + wave * 1024 + lane * 16;                           \
        char* ldst_ = &buf[IB][0] + wave * 1024;                                      \
        _Pragma("unroll")                                                             \
        for (int j_ = 0; j_ < 8; ++j_) {                                              \
            __builtin_amdgcn_global_load_lds(                                         \
                (const __attribute__((address_space(1))) void*)(gsrc_ + j_ * 4096),   \
                (__attribute__((address_space(3))) void*)(ldst_ + j_ * 4096), 16, 0, 0); \
        }                                                                             \
        if (wave == 0) {                                                              \
            __builtin_amdgcn_global_load_lds(                                         \
                (const __attribute__((address_space(1))) void*)(rec_ + N2_OFF + lane * 16), \
                (__attribute__((address_space(3))) void*)(&buf[IB][0] + N2_OFF), 16, 0, 0); \
        }                                                                             \
    } while (0)

    // ---- prologue: DMA first chunk, load stationary A fragments (2 row-tiles) ----
    int c = cb;
    DMAISSUE(c, 0);
    f16x8 af[2][8];
#pragma unroll
    for (int tb = 0; tb < 2; ++tb) {
        const f16x8* ap = (const f16x8*)(A + (size_t)(rowbase + tb * 16 + rcol) * HID + q * 8);
#pragma unroll
        for (int s = 0; s < 8; ++s) af[tb][s] = ap[s * 4];
    }
    // online softmax state per row-tile (per-lane: row rcol x key-quad q slice)
    float M[2]  = {-3e38f, -3e38f};
    float Lr[2] = {0.f, 0.f};
    float Ar[2] = {0.f, 0.f};
    __syncthreads();   // drains vmcnt: chunk0 DMA + af loads

    int ib = 0;
#pragma unroll 1
    for (; c < NCHUNK; ) {
        const int cn = c + CBLK;
        if (cn < NCHUNK) DMAISSUE(cn, ib ^ 1);   // prefetch next chunk

        const _Float16* bt16 = (const _Float16*)&buf[ib][0];
        const float* n2s = (const float*)(&buf[ib][0] + N2_OFF);
        const float* vvs = n2s + 64;

        // acc init = nn: MFMA C-in carries -||k||^2*log2e (reg r <-> key q*4+r)
        f32x4 acc[2][4];
#pragma unroll
        for (int cc = 0; cc < 4; ++cc) {
            const f32x4 nn = *(const f32x4*)&n2s[cc * 16 + q * 4];
            acc[0][cc] = nn;
            acc[1][cc] = nn;
        }
#pragma unroll
        for (int s = 0; s < 8; ++s) {
#pragma unroll
            for (int cc = 0; cc < 4; ++cc) {
                const f16x8 bf = *(const f16x8*)(bt16 + (((s * 4 + q) * 64 + cc * 16 + rcol) << 3));
                // swapped operands: C[key][row]; one bf read feeds both row-tiles
                acc[0][cc] = __builtin_amdgcn_mfma_f32_16x16x32_f16(bf, af[0][s], acc[0][cc], 0, 0, 0);
                acc[1][cc] = __builtin_amdgcn_mfma_f32_16x16x32_f16(bf, af[1][s], acc[1][cc], 0, 0, 0);
            }
        }

        // ---- per-chunk ONLINE update; acc already holds base-2 logits ----
#pragma unroll
        for (int tb = 0; tb < 2; ++tb) {
            const f32x4 mv = __builtin_elementwise_max(
                __builtin_elementwise_max(acc[tb][0], acc[tb][1]),
                __builtin_elementwise_max(acc[tb][2], acc[tb][3]));
            const float pmax = fmaxf(fmaxf(mv[0], mv[1]), fmaxf(mv[2], mv[3]));
            const float Mn = fmaxf(M[tb], pmax);
            const float sc = exp2f(M[tb] - Mn);   // first chunk: exp2(-inf)=0, L=A=0 anyway
            const f32x4 Mn4 = {Mn, Mn, Mn, Mn};
            f32x4 ws  = {0.f, 0.f, 0.f, 0.f};
            f32x4 wvs = {0.f, 0.f, 0.f, 0.f};
#pragma unroll
            for (int cc = 0; cc < 4; ++cc) {
                const f32x4 e = acc[tb][cc] - Mn4;
                const f32x4 w = {exp2f(e[0]), exp2f(e[1]), exp2f(e[2]), exp2f(e[3])};
                const f32x4 vl = *(const f32x4*)&vvs[cc * 16 + q * 4];
                ws  += w;
                wvs += w * vl;
            }
            const float ls = (ws[0] + ws[1]) + (ws[2] + ws[3]);
            const float as = (wvs[0] + wvs[1]) + (wvs[2] + wvs[3]);
            Lr[tb] = fmaf(Lr[tb], sc, ls);
            Ar[tb] = fmaf(Ar[tb], sc, as);
            M[tb] = Mn;
        }

        __syncthreads();   // next DMA drained + all reads of buf[ib] done
        c = cn; ib ^= 1;
    }
#undef DMAISSUE

    // ---- epilogue: merge across the 4 q-lanes of each row, write one partial ----
#pragma unroll
    for (int tb = 0; tb < 2; ++tb) {
        float m = M[tb], l = Lr[tb], a = Ar[tb];
#pragma unroll
        for (int sh = 16; sh < 64; sh <<= 1) {
            const float mo = __shfl_xor(m, sh, 64);
            const float lo = __shfl_xor(l, sh, 64);
            const float ao = __shfl_xor(a, sh, 64);
            const float mn = fmaxf(m, mo);
            const float s0 = exp2f(m - mn);
            const float s1 = exp2f(mo - mn);
            l = fmaf(l, s0, lo * s1);
            a = fmaf(a, s0, ao * s1);
            m = mn;
        }
        if (lane < 16) {
            const int row = rowbase + tb * 16 + lane;
            const size_t idx = (size_t)cb * BATCH + row;
            pm[idx] = m; pl[idx] = l; pa[idx] = a;
        }
    }
}

// ------------- single merge: 64-way per row, write q1==q2 -------------
__global__ __launch_bounds__(256) void np_merge(const float* __restrict__ pm,
                                                const float* __restrict__ pl,
                                                const float* __restrict__ pa,
                                                float* __restrict__ out) {
    const int t = threadIdx.x;
    const int row = blockIdx.x * 64 + (t & 63);
    const int cg = t >> 6;
    float M = -3e38f, L = 0.f, Acc = 0.f;
#pragma unroll 1
    for (int cb = cg; cb < CBLK; cb += 4) {
        const size_t idx = (size_t)cb * BATCH + row;
        const float m = pm[idx], l = pl[idx], a = pa[idx];
        const float Mn = fmaxf(M, m);
        const float s0 = exp2f(M - Mn);
        const float s1 = exp2f(m - Mn);
        L = fmaf(L, s0, l * s1);
        Acc = fmaf(Acc, s0, a * s1);
        M = Mn;
    }
    __shared__ float sm[256], sl[256], sa[256];
    sm[t] = M; sl[t] = L; sa[t] = Acc;
    __syncthreads();
    if (t < 64) {
        const float M0 = sm[t], M1 = sm[t + 64], M2 = sm[t + 128], M3 = sm[t + 192];
        const float Mf = fmaxf(fmaxf(M0, M1), fmaxf(M2, M3));
        const float e0 = exp2f(M0 - Mf), e1 = exp2f(M1 - Mf), e2 = exp2f(M2 - Mf), e3 = exp2f(M3 - Mf);
        const float Lf = sl[t] * e0 + sl[t + 64] * e1 + sl[t + 128] * e2 + sl[t + 192] * e3;
        const float Af = sa[t] * e0 + sa[t + 64] * e1 + sa[t + 128] * e2 + sa[t + 192] * e3;
        const float qv = Af / Lf;
        const int r = blockIdx.x * 64 + t;
        out[r] = qv;
        out[BATCH + r] = qv;
    }
}

extern "C" void kernel_launch(void* const* d_in, const int* in_sizes, int n_in,
                              void* d_out, int out_size, void* d_ws, size_t ws_size,
                              hipStream_t stream) {
    const float* obs   = (const float*)d_in[0];
    const float* act   = (const float*)d_in[1];
    const float* W     = (const float*)d_in[2];
    const float* bias  = (const float*)d_in[3];
    const float* gamma = (const float*)d_in[4];
    const float* beta  = (const float*)d_in[5];
    const float* keys  = (const float*)d_in[6];
    const float* vals  = (const float*)d_in[7];
    float* out = (float*)d_out;

    char* w = (char*)d_ws;
    char* keys16c = w;                                     // 52.8 MB records
    w += (size_t)NCHUNK * REC_BYTES;
    _Float16* A = (_Float16*)w;                            // 512 KB
    w += (size_t)BATCH * HID * sizeof(_Float16);
    float* pm = (float*)w;                                 // 3 x 256 KB
    float* pl = pm + (size_t)CBLK * BATCH;
    float* pa = pl + (size_t)CBLK * BATCH;

    np_pre<<<NCHUNK + BATCH, 256, 0, stream>>>(obs, act, W, bias, gamma, beta,
                                               keys, vals, keys16c, A);
    np_gemm<<<NRT * CBLK, 256, 0, stream>>>(keys16c, A, pm, pl, pa);
    np_merge<<<BATCH / 64, 256, 0, stream>>>(pm, pl, pa, out);
}